// Round 1
// baseline (33528.500 us; speedup 1.0000x reference)
//
#include <hip/hip_runtime.h>
#include <math.h>

// ---------------------------------------------------------------------------
// Temporal CfC layer on MI355X.
//  B=32, T=512, D=1024, U=1024, CAT=2048, BB=2048.
//  Structure: LN -> GEMM_in -> persistent cooperative scan (512 steps x 3
//  phases, hand-rolled grid barrier) -> GEMM_out (+residual).
//  All matmuls bf16 MFMA 16x16x32, fp32 accumulate.
// ---------------------------------------------------------------------------

#define G_SCAN 128   // scan workgroups (<= 256 CUs -> co-resident)

using bfrag = __attribute__((ext_vector_type(8))) short;   // 8 bf16
using ffrag = __attribute__((ext_vector_type(4))) float;   // 4 f32 acc

__device__ __forceinline__ short f2bf(float f) {           // RNE f32->bf16
  union { float f; unsigned u; } v; v.f = f;
  unsigned r = (v.u + 0x7fffu + ((v.u >> 16) & 1u)) >> 16;
  return (short)(unsigned short)r;
}

__device__ __forceinline__ ffrag mfma16(bfrag a, bfrag b, ffrag c) {
  return __builtin_amdgcn_mfma_f32_16x16x32_bf16(a, b, c, 0, 0, 0);
}

// ----------------------------- workspace layout ----------------------------
constexpr size_t OFF_FLAGS = 0;                                  // 128 u32
constexpr size_t OFF_CFCX  = 1024;                               // [T][B][1024] bf16 (reused as outs)
constexpr size_t OFF_XN    = OFF_CFCX + (size_t)512*32*1024*2;   // [16384][1024] bf16
constexpr size_t OFF_A1    = OFF_XN   + (size_t)16384*1024*2;    // [32][2048] bf16
constexpr size_t OFF_A2    = OFF_A1   + (size_t)32*2048*2;
constexpr size_t OFF_H     = OFF_A2   + (size_t)32*2048*2;       // [32][1024] bf16
constexpr size_t OFF_WINP  = OFF_H    + (size_t)32*1024*2;       // packed w_in
constexpr size_t OFF_W0P   = OFF_WINP + (size_t)1024*1024*2;     // packed bb_w[0]
constexpr size_t OFF_W1P   = OFF_W0P  + (size_t)2048*2048*2;     // packed bb_w[1]
constexpr size_t OFF_WBP   = OFF_W1P  + (size_t)2048*2048*2;     // packed ff1,ff2,ta,tb
constexpr size_t OFF_WOUTP = OFF_WBP  + (size_t)4*2048*1024*2;   // packed w_out

// ----------------------------- init ----------------------------------------
__global__ void init_kernel(const float* __restrict__ hidden,
                            short* __restrict__ hbuf, unsigned* __restrict__ flags) {
  int i = blockIdx.x * 256 + threadIdx.x;
  if (i < 32 * 1024) hbuf[i] = f2bf(hidden[i]);
  if (i < 128) flags[i] = 0u;
}

// ----------------------------- layernorm ------------------------------------
__global__ void __launch_bounds__(256) ln_kernel(const float* __restrict__ x,
                                                 const float* __restrict__ gw,
                                                 const float* __restrict__ gb,
                                                 short* __restrict__ xn) {
  int row = blockIdx.x, tid = threadIdx.x;
  const float4* xr = (const float4*)(x + (size_t)row * 1024);
  float4 v = xr[tid];
  float s  = v.x + v.y + v.z + v.w;
  float sq = v.x*v.x + v.y*v.y + v.z*v.z + v.w*v.w;
  for (int off = 32; off; off >>= 1) { s += __shfl_down(s, off); sq += __shfl_down(sq, off); }
  __shared__ float as[4], aq[4], st[2];
  if ((tid & 63) == 0) { as[tid >> 6] = s; aq[tid >> 6] = sq; }
  __syncthreads();
  if (tid == 0) {
    float S = as[0]+as[1]+as[2]+as[3], Q = aq[0]+aq[1]+aq[2]+aq[3];
    float mean = S * (1.f/1024.f);
    float var  = Q * (1.f/1024.f) - mean*mean;
    st[0] = mean; st[1] = rsqrtf(var + 1e-5f);
  }
  __syncthreads();
  float mean = st[0], rstd = st[1];
  int i = tid * 4;
  float a0 = (v.x-mean)*rstd*gw[i]   + gb[i];
  float a1 = (v.y-mean)*rstd*gw[i+1] + gb[i+1];
  float a2 = (v.z-mean)*rstd*gw[i+2] + gb[i+2];
  float a3 = (v.w-mean)*rstd*gw[i+3] + gb[i+3];
  unsigned lo = ((unsigned)(unsigned short)f2bf(a0)) | (((unsigned)(unsigned short)f2bf(a1)) << 16);
  unsigned hi = ((unsigned)(unsigned short)f2bf(a2)) | (((unsigned)(unsigned short)f2bf(a3)) << 16);
  ((uint2*)(xn + (size_t)row * 1024))[tid] = make_uint2(lo, hi);
}

// -------- pack fp32 [K][N] weights into bf16 MFMA B-fragment order ----------
// dst layout: [nt = n/16][kt = k/32][lane 0..63][8 bf16], lane&15 = n, lane>>4
// selects k-subblock of 8. One 64-thread block per (nt,kt) chunk.
__global__ void pack_frag(const float* __restrict__ src, short* __restrict__ dst,
                          int ktiles, int N) {
  int chunk = blockIdx.x;
  int nt = chunk / ktiles, kt = chunk - nt * ktiles;
  int lane = threadIdx.x;
  int n  = nt * 16 + (lane & 15);
  int kb = kt * 32 + (lane >> 4) * 8;
  bfrag v;
#pragma unroll
  for (int j = 0; j < 8; ++j) v[j] = f2bf(src[(size_t)(kb + j) * N + n]);
  *(bfrag*)(dst + ((size_t)chunk * 64 + lane) * 8) = v;
}

// ----------------------------- GEMMs ----------------------------------------
// C-tile 64x64, 4 waves each own 16 cols; A staged in LDS (padded), B from
// packed fragments.  gemm_in: xn[b*512+t][1024] -> cfc_x[t][b][e] bf16.
__global__ void __launch_bounds__(256) gemm_in_kernel(const short* __restrict__ A,
                                                      const short* __restrict__ Bp,
                                                      const float* __restrict__ bias,
                                                      short* __restrict__ C) {
  __shared__ short At[64][72];
  int tid = threadIdx.x, wave = tid >> 6, lane = tid & 63, l15 = lane & 15, q = lane >> 4;
  int row0 = blockIdx.x * 64, col0 = blockIdx.y * 64;
  ffrag acc[4] = {{0,0,0,0},{0,0,0,0},{0,0,0,0},{0,0,0,0}};
  int nt = (col0 >> 4) + wave;
  const short* bp = Bp + (size_t)nt * 32 * 512 + lane * 8;   // ktiles = 32
  int r = tid >> 2, cs = (tid & 3) * 16;
  const short* asrc = A + (size_t)(row0 + r) * 1024 + cs;
  for (int k0 = 0; k0 < 1024; k0 += 64) {
    __syncthreads();
    *(bfrag*)&At[r][cs]     = *(const bfrag*)(asrc + k0);
    *(bfrag*)&At[r][cs + 8] = *(const bfrag*)(asrc + k0 + 8);
    __syncthreads();
#pragma unroll
    for (int kk = 0; kk < 64; kk += 32) {
      bfrag b = *(const bfrag*)(bp + (size_t)((k0 + kk) >> 5) * 512);
#pragma unroll
      for (int mt = 0; mt < 4; ++mt) {
        bfrag a = *(const bfrag*)&At[mt*16 + l15][kk + q*8];
        acc[mt] = mfma16(a, b, acc[mt]);
      }
    }
  }
  int ecol = col0 + wave * 16 + l15;
  float bs = bias[ecol];
#pragma unroll
  for (int mt = 0; mt < 4; ++mt)
#pragma unroll
    for (int rr = 0; rr < 4; ++rr) {
      int mrow = row0 + mt*16 + q*4 + rr;
      int b = mrow >> 9, t = mrow & 511;
      C[((size_t)t * 32 + b) * 1024 + ecol] = f2bf(acc[mt][rr] + bs);
    }
}

// gemm_out: outs[t*32+b][1024] @ w_out + b_out + x -> y[b][t][d] fp32
__global__ void __launch_bounds__(256) gemm_out_kernel(const short* __restrict__ A,
                                                       const short* __restrict__ Bp,
                                                       const float* __restrict__ bias,
                                                       const float* __restrict__ X,
                                                       float* __restrict__ Y) {
  __shared__ short At[64][72];
  int tid = threadIdx.x, wave = tid >> 6, lane = tid & 63, l15 = lane & 15, q = lane >> 4;
  int row0 = blockIdx.x * 64, col0 = blockIdx.y * 64;
  ffrag acc[4] = {{0,0,0,0},{0,0,0,0},{0,0,0,0},{0,0,0,0}};
  int nt = (col0 >> 4) + wave;
  const short* bp = Bp + (size_t)nt * 32 * 512 + lane * 8;
  int r = tid >> 2, cs = (tid & 3) * 16;
  const short* asrc = A + (size_t)(row0 + r) * 1024 + cs;
  for (int k0 = 0; k0 < 1024; k0 += 64) {
    __syncthreads();
    *(bfrag*)&At[r][cs]     = *(const bfrag*)(asrc + k0);
    *(bfrag*)&At[r][cs + 8] = *(const bfrag*)(asrc + k0 + 8);
    __syncthreads();
#pragma unroll
    for (int kk = 0; kk < 64; kk += 32) {
      bfrag b = *(const bfrag*)(bp + (size_t)((k0 + kk) >> 5) * 512);
#pragma unroll
      for (int mt = 0; mt < 4; ++mt) {
        bfrag a = *(const bfrag*)&At[mt*16 + l15][kk + q*8];
        acc[mt] = mfma16(a, b, acc[mt]);
      }
    }
  }
  int ecol = col0 + wave * 16 + l15;
  float bs = bias[ecol];
#pragma unroll
  for (int mt = 0; mt < 4; ++mt)
#pragma unroll
    for (int rr = 0; rr < 4; ++rr) {
      int mrow = row0 + mt*16 + q*4 + rr;
      int t = mrow >> 5, b = mrow & 31;
      size_t yi = ((size_t)b * 512 + t) * 1024 + ecol;
      Y[yi] = X[yi] + acc[mt][rr] + bs;
    }
}

// ----------------------------- scan -----------------------------------------
// Grid barrier: per-WG flag store + 128-lane gang poll. No atomic RMW
// serialization; monotonic barrier index, flags zeroed by init_kernel.
__device__ __forceinline__ void gridbar(unsigned* flags, unsigned idx, int tid, int wg) {
  __syncthreads();                        // drains all waves' vm/lds ops
  if (tid == 0) {
    __threadfence();                      // release (L2 writeback, device scope)
    __hip_atomic_store(&flags[wg], idx, __ATOMIC_RELAXED, __HIP_MEMORY_SCOPE_AGENT);
  }
  int ok;
  do {
    ok = 1;
    if (tid < G_SCAN)
      ok = (__hip_atomic_load(&flags[tid], __ATOMIC_RELAXED, __HIP_MEMORY_SCOPE_AGENT) >= idx);
  } while (__syncthreads_and(ok) == 0);
  __threadfence();                        // acquire (invalidate stale lines)
}

// one MLP stage: OUT[32, 16cols of this WG] = A[32,2048] @ Wslice, K-split
// over the 4 waves, partials to LDS.
__device__ __forceinline__ void mm_phase(const short* __restrict__ Ab, int astride, int kcol0,
                                         const short* __restrict__ Bf,
                                         float red[4][4][16][16], int wave, int lane) {
  int l15 = lane & 15, q = lane >> 4;
  ffrag c0 = {0,0,0,0}, c1 = {0,0,0,0};
  const short* a0 = Ab + (size_t)l15 * astride + kcol0 + q * 8;
  const short* a1 = a0 + (size_t)16 * astride;
#pragma unroll
  for (int ki = 0; ki < 16; ++ki) {
    bfrag av0 = *(const bfrag*)(a0 + ki * 32);
    bfrag av1 = *(const bfrag*)(a1 + ki * 32);
    bfrag bv  = *(const bfrag*)(Bf + (size_t)ki * 512);
    c0 = mfma16(av0, bv, c0);
    c1 = mfma16(av1, bv, c1);
  }
#pragma unroll
  for (int rr = 0; rr < 4; ++rr) {
    red[wave][0][q*4 + rr][l15] = c0[rr];
    red[wave][1][q*4 + rr][l15] = c1[rr];
  }
}

__device__ __forceinline__ void lecun_store(float red[4][4][16][16],
                                            const float* __restrict__ bias,
                                            short* __restrict__ dst, int n0, int tid) {
  for (int e = tid; e < 512; e += 256) {
    int mt = e >> 8, row = (e >> 4) & 15, col = e & 15;
    float s = red[0][mt][row][col] + red[1][mt][row][col]
            + red[2][mt][row][col] + red[3][mt][row][col];
    s += bias[n0 + col];
    s = 1.7159f * tanhf(0.666f * s);
    dst[(size_t)(mt*16 + row) * 2048 + n0 + col] = f2bf(s);
  }
}

__global__ void __launch_bounds__(256, 1) scan_kernel(
    const short* cfcx, const short* __restrict__ W0p, const short* __restrict__ W1p,
    const short* __restrict__ Wbp, const float* __restrict__ bbb,
    const float* __restrict__ bf1, const float* __restrict__ bf2,
    const float* __restrict__ bta, const float* __restrict__ btb,
    const float* __restrict__ tsp, short* __restrict__ A1, short* __restrict__ A2,
    short* __restrict__ hbuf, short* outs, float* __restrict__ hfinal,
    unsigned* flags) {
  __shared__ float red[4][4][16][16];   // 16 KB
  const int w = blockIdx.x, tid = threadIdx.x;
  const int wave = tid >> 6, lane = tid & 63, l15 = lane & 15, q = lane >> 4;
  unsigned bar = 0;
  const int mt3 = w & 1, j3 = w >> 1;                     // phase-3 split
  const short* B1 = W0p + ((size_t)w * 64 + wave * 16) * 512 + lane * 8;
  const short* B2 = W1p + ((size_t)w * 64 + wave * 16) * 512 + lane * 8;
  const short* B3[4];
#pragma unroll
  for (int m = 0; m < 4; ++m)
    B3[m] = Wbp + (((size_t)(m * 64 + j3) * 64) + wave * 16) * 512 + lane * 8;

  for (int t = 0; t < 512; ++t) {
    // -------- phase 1: A1 = lecun_tanh([x_t | h] @ W0 + b0) --------
    {
      const short* Ab; int kc0;
      if (wave < 2) { Ab = cfcx + ((size_t)t << 15); kc0 = wave * 512; }
      else          { Ab = hbuf;                     kc0 = (wave - 2) * 512; }
      mm_phase(Ab, 1024, kc0, B1, red, wave, lane);
      __syncthreads();
      lecun_store(red, bbb, A1, w * 16, tid);
      gridbar(flags, ++bar, tid, w);
    }
    // -------- phase 2: A2 = lecun_tanh(A1 @ W1 + b1) --------
    {
      mm_phase(A1, 2048, wave * 512, B2, red, wave, lane);
      __syncthreads();
      lecun_store(red, bbb + 2048, A2, w * 16, tid);
      gridbar(flags, ++bar, tid, w);
    }
    // -------- phase 3: branch matmuls + CfC interpolation --------
    {
      ffrag c[4] = {{0,0,0,0},{0,0,0,0},{0,0,0,0},{0,0,0,0}};
      const short* ap = A2 + (size_t)(mt3 * 16 + l15) * 2048 + wave * 512 + q * 8;
#pragma unroll 4
      for (int ki = 0; ki < 16; ++ki) {
        bfrag a = *(const bfrag*)(ap + ki * 32);
#pragma unroll
        for (int m = 0; m < 4; ++m) {
          bfrag b = *(const bfrag*)(B3[m] + (size_t)ki * 512);
          c[m] = mfma16(a, b, c[m]);
        }
      }
#pragma unroll
      for (int m = 0; m < 4; ++m)
#pragma unroll
        for (int rr = 0; rr < 4; ++rr) red[wave][m][q*4 + rr][l15] = c[m][rr];
      __syncthreads();
      {
        int row = tid >> 4, col = tid & 15;
        int b = mt3 * 16 + row, u = j3 * 16 + col;
        float s1 = red[0][0][row][col] + red[1][0][row][col] + red[2][0][row][col] + red[3][0][row][col] + bf1[u];
        float s2 = red[0][1][row][col] + red[1][1][row][col] + red[2][1][row][col] + red[3][1][row][col] + bf2[u];
        float sa = red[0][2][row][col] + red[1][2][row][col] + red[2][2][row][col] + red[3][2][row][col] + bta[u];
        float sb = red[0][3][row][col] + red[1][3][row][col] + red[2][3][row][col] + red[3][3][row][col] + btb[u];
        float ts = tsp[b * 512 + t];
        float sg = 1.f / (1.f + expf(-(sa * ts + sb)));
        float hn = tanhf(s1) * (1.f - sg) + sg * tanhf(s2);
        short hb = f2bf(hn);
        hbuf[b * 1024 + u] = hb;
        outs[((size_t)t * 32 + b) * 1024 + u] = hb;   // overwrites dead cfc_x[t]
        if (t == 511) hfinal[b * 1024 + u] = hn;
      }
      gridbar(flags, ++bar, tid, w);
    }
  }
}

// ----------------------------- launch ---------------------------------------
extern "C" void kernel_launch(void* const* d_in, const int* in_sizes, int n_in,
                              void* d_out, int out_size, void* d_ws, size_t ws_size,
                              hipStream_t stream) {
  (void)in_sizes; (void)n_in; (void)out_size; (void)ws_size;
  const float* x      = (const float*)d_in[0];
  const float* tsp    = (const float*)d_in[1];
  const float* hidden = (const float*)d_in[2];
  const float* norm_w = (const float*)d_in[3];
  const float* norm_b = (const float*)d_in[4];
  const float* w_in   = (const float*)d_in[5];
  const float* b_in   = (const float*)d_in[6];
  const float* bb_w   = (const float*)d_in[7];
  const float* bb_b   = (const float*)d_in[8];
  const float* w_ff1  = (const float*)d_in[9];
  const float* b_ff1  = (const float*)d_in[10];
  const float* w_ff2  = (const float*)d_in[11];
  const float* b_ff2  = (const float*)d_in[12];
  const float* w_ta   = (const float*)d_in[13];
  const float* b_ta   = (const float*)d_in[14];
  const float* w_tb   = (const float*)d_in[15];
  const float* b_tb   = (const float*)d_in[16];
  const float* w_out  = (const float*)d_in[17];
  const float* b_out  = (const float*)d_in[18];

  float* y      = (float*)d_out;
  float* hfinal = y + (size_t)32 * 512 * 1024;

  char* ws = (char*)d_ws;
  unsigned* flags = (unsigned*)(ws + OFF_FLAGS);
  short* cfcx  = (short*)(ws + OFF_CFCX);
  short* xn    = (short*)(ws + OFF_XN);
  short* A1    = (short*)(ws + OFF_A1);
  short* A2    = (short*)(ws + OFF_A2);
  short* hbuf  = (short*)(ws + OFF_H);
  short* winp  = (short*)(ws + OFF_WINP);
  short* w0p   = (short*)(ws + OFF_W0P);
  short* w1p   = (short*)(ws + OFF_W1P);
  short* wbp   = (short*)(ws + OFF_WBP);
  short* woutp = (short*)(ws + OFF_WOUTP);
  short* outs  = cfcx;   // outs[t] overwrites dead cfc_x[t] slice

  init_kernel<<<128, 256, 0, stream>>>(hidden, hbuf, flags);
  ln_kernel<<<16384, 256, 0, stream>>>(x, norm_w, norm_b, xn);

  pack_frag<<<2048, 64, 0, stream>>>(w_in, winp, 32, 1024);
  pack_frag<<<8192, 64, 0, stream>>>(bb_w, w0p, 64, 2048);
  pack_frag<<<8192, 64, 0, stream>>>(bb_w + (size_t)2048*2048, w1p, 64, 2048);
  pack_frag<<<4096, 64, 0, stream>>>(w_ff1, wbp + (size_t)0*2097152, 64, 1024);
  pack_frag<<<4096, 64, 0, stream>>>(w_ff2, wbp + (size_t)1*2097152, 64, 1024);
  pack_frag<<<4096, 64, 0, stream>>>(w_ta,  wbp + (size_t)2*2097152, 64, 1024);
  pack_frag<<<4096, 64, 0, stream>>>(w_tb,  wbp + (size_t)3*2097152, 64, 1024);
  pack_frag<<<2048, 64, 0, stream>>>(w_out, woutp, 32, 1024);

  gemm_in_kernel<<<dim3(256, 16), 256, 0, stream>>>(xn, winp, b_in, cfcx);

  void* args[] = {&cfcx, &w0p, &w1p, &wbp, &bb_b, &b_ff1, &b_ff2, &b_ta, &b_tb,
                  &tsp, &A1, &A2, &hbuf, &outs, &hfinal, &flags};
  hipLaunchCooperativeKernel(reinterpret_cast<const void*>(&scan_kernel),
                             dim3(G_SCAN), dim3(256), args, 0, stream);

  gemm_out_kernel<<<dim3(256, 16), 256, 0, stream>>>(outs, woutp, b_out, x, y);
}

// Round 3
// 18638.951 us; speedup vs baseline: 1.7988x; 1.7988x over previous
//
#include <hip/hip_runtime.h>
#include <math.h>

// ---------------------------------------------------------------------------
// Temporal CfC layer on MI355X.  B=32, T=512, D=1024, U=1024, CAT=2048, BB=2048.
//  LN -> GEMM_in -> persistent cooperative WG-specialized scan -> GEMM_out.
//  Scan: 256 WGs in 3 groups (P1:64 / P2:64 / P3:128). Each WG holds its
//  weight slice in LDS (128 KB, packed MFMA B-frag order) -> immune to the
//  L2 invalidate that the conservative __threadfence() protocol performs.
//  Producer->consumer signaling uses R1's PROVEN pattern: __syncthreads ->
//  tid0 {__threadfence(); relaxed agent flag store} -> consumer poll ->
//  tid0 __threadfence() -> __syncthreads -> plain reads.
// ---------------------------------------------------------------------------

using bfrag = __attribute__((ext_vector_type(8))) short;   // 8 bf16
using ffrag = __attribute__((ext_vector_type(4))) float;   // 4 f32 acc

__device__ __forceinline__ short f2bf(float f) {           // RNE f32->bf16
  union { float f; unsigned u; } v; v.f = f;
  unsigned r = (v.u + 0x7fffu + ((v.u >> 16) & 1u)) >> 16;
  return (short)(unsigned short)r;
}

__device__ __forceinline__ unsigned pack2(short lo, short hi) {
  return ((unsigned)(unsigned short)lo) | (((unsigned)(unsigned short)hi) << 16);
}

__device__ __forceinline__ ffrag mfma16(bfrag a, bfrag b, ffrag c) {
  return __builtin_amdgcn_mfma_f32_16x16x32_bf16(a, b, c, 0, 0, 0);
}

// ----------------------------- workspace layout ----------------------------
constexpr size_t OFF_FLAGS = 0;                                  // 256 u32 = 1 KB
constexpr size_t OFF_CFCX  = 1024;                               // [T][B][1024] bf16 (reused as outs)
constexpr size_t OFF_XN    = OFF_CFCX + (size_t)512*32*1024*2;   // [16384][1024] bf16
constexpr size_t OFF_A1    = OFF_XN   + (size_t)16384*1024*2;    // [32][2048] bf16
constexpr size_t OFF_A2    = OFF_A1   + (size_t)32*2048*2;
constexpr size_t OFF_H     = OFF_A2   + (size_t)32*2048*2;       // [32][1024] bf16
constexpr size_t OFF_WINP  = OFF_H    + (size_t)32*1024*2;       // packed w_in
constexpr size_t OFF_W0P   = OFF_WINP + (size_t)1024*1024*2;     // packed bb_w[0] (K=2048)
constexpr size_t OFF_W1P   = OFF_W0P  + (size_t)2048*2048*2;     // packed bb_w[1]
constexpr size_t OFF_WBP   = OFF_W1P  + (size_t)2048*2048*2;     // packed branch mats (P3 layout)
constexpr size_t OFF_WOUTP = OFF_WBP  + (size_t)4*2048*1024*2;   // packed w_out

// ----------------------------- init ----------------------------------------
__global__ void init_kernel(const float* __restrict__ hidden,
                            short* __restrict__ hbuf, unsigned* __restrict__ flags) {
  int i = blockIdx.x * 256 + threadIdx.x;
  if (i < 32 * 1024) hbuf[i] = f2bf(hidden[i]);
  if (i < 256) flags[i] = 0u;
}

// ----------------------------- layernorm ------------------------------------
__global__ void __launch_bounds__(256) ln_kernel(const float* __restrict__ x,
                                                 const float* __restrict__ gw,
                                                 const float* __restrict__ gb,
                                                 short* __restrict__ xn) {
  int row = blockIdx.x, tid = threadIdx.x;
  const float4* xr = (const float4*)(x + (size_t)row * 1024);
  float4 v = xr[tid];
  float s  = v.x + v.y + v.z + v.w;
  float sq = v.x*v.x + v.y*v.y + v.z*v.z + v.w*v.w;
  for (int off = 32; off; off >>= 1) { s += __shfl_down(s, off); sq += __shfl_down(sq, off); }
  __shared__ float as[4], aq[4], st[2];
  if ((tid & 63) == 0) { as[tid >> 6] = s; aq[tid >> 6] = sq; }
  __syncthreads();
  if (tid == 0) {
    float S = as[0]+as[1]+as[2]+as[3], Q = aq[0]+aq[1]+aq[2]+aq[3];
    float mean = S * (1.f/1024.f);
    float var  = Q * (1.f/1024.f) - mean*mean;
    st[0] = mean; st[1] = rsqrtf(var + 1e-5f);
  }
  __syncthreads();
  float mean = st[0], rstd = st[1];
  int i = tid * 4;
  float a0 = (v.x-mean)*rstd*gw[i]   + gb[i];
  float a1 = (v.y-mean)*rstd*gw[i+1] + gb[i+1];
  float a2 = (v.z-mean)*rstd*gw[i+2] + gb[i+2];
  float a3 = (v.w-mean)*rstd*gw[i+3] + gb[i+3];
  unsigned lo = pack2(f2bf(a0), f2bf(a1));
  unsigned hi = pack2(f2bf(a2), f2bf(a3));
  ((uint2*)(xn + (size_t)row * 1024))[tid] = make_uint2(lo, hi);
}

// -------- pack fp32 [K][N] weights into bf16 MFMA B-fragment order ----------
// dst: [nt][kt][lane][8]; entry = src[kt*32 + (lane>>4)*8 + j][nt*16 + (lane&15)]
__global__ void pack_frag(const float* __restrict__ src, short* __restrict__ dst,
                          int ktiles, int N) {
  int chunk = blockIdx.x;
  int nt = chunk / ktiles, kt = chunk - nt * ktiles;
  int lane = threadIdx.x;
  int n  = nt * 16 + (lane & 15);
  int kb = kt * 32 + (lane >> 4) * 8;
  bfrag v;
#pragma unroll
  for (int j = 0; j < 8; ++j) v[j] = f2bf(src[(size_t)(kb + j) * N + n]);
  *(bfrag*)(dst + ((size_t)chunk * 64 + lane) * 8) = v;
}

// -------- pack branch mats for P3: per-WG [j=128][ntL=2][kt=64][lane][8] ----
// Logical 32-col B per WG j: cols 0-7=ff1[j*8..], 8-15=ff2, 16-23=ta, 24-31=tb.
__global__ void pack_bb3(const float* __restrict__ f1, const float* __restrict__ f2,
                         const float* __restrict__ ta, const float* __restrict__ tb,
                         short* __restrict__ dst) {
  int chunk = blockIdx.x;                 // ((j*2 + ntL)*64 + kt)
  int kt = chunk & 63, ntL = (chunk >> 6) & 1, j = chunk >> 7;
  int l = threadIdx.x, l15 = l & 15, q = l >> 4;
  int mat = ntL * 2 + (l15 >> 3);
  int col = j * 8 + (l15 & 7);
  const float* src = (mat == 0 ? f1 : mat == 1 ? f2 : mat == 2 ? ta : tb);
  int k0 = kt * 32 + q * 8;
  bfrag v;
#pragma unroll
  for (int jj = 0; jj < 8; ++jj) v[jj] = f2bf(src[(size_t)(k0 + jj) * 1024 + col]);
  *(bfrag*)(dst + ((size_t)chunk * 64 + l) * 8) = v;
}

// ----------------------------- GEMMs ----------------------------------------
__global__ void __launch_bounds__(256) gemm_in_kernel(const short* __restrict__ A,
                                                      const short* __restrict__ Bp,
                                                      const float* __restrict__ bias,
                                                      short* __restrict__ C) {
  __shared__ short At[64][72];
  int tid = threadIdx.x, wave = tid >> 6, lane = tid & 63, l15 = lane & 15, q = lane >> 4;
  int row0 = blockIdx.x * 64, col0 = blockIdx.y * 64;
  ffrag acc[4] = {{0,0,0,0},{0,0,0,0},{0,0,0,0},{0,0,0,0}};
  int nt = (col0 >> 4) + wave;
  const short* bp = Bp + (size_t)nt * 32 * 512 + lane * 8;   // ktiles = 32
  int r = tid >> 2, cs = (tid & 3) * 16;
  const short* asrc = A + (size_t)(row0 + r) * 1024 + cs;
  for (int k0 = 0; k0 < 1024; k0 += 64) {
    __syncthreads();
    *(bfrag*)&At[r][cs]     = *(const bfrag*)(asrc + k0);
    *(bfrag*)&At[r][cs + 8] = *(const bfrag*)(asrc + k0 + 8);
    __syncthreads();
#pragma unroll
    for (int kk = 0; kk < 64; kk += 32) {
      bfrag b = *(const bfrag*)(bp + (size_t)((k0 + kk) >> 5) * 512);
#pragma unroll
      for (int mt = 0; mt < 4; ++mt) {
        bfrag a = *(const bfrag*)&At[mt*16 + l15][kk + q*8];
        acc[mt] = mfma16(a, b, acc[mt]);
      }
    }
  }
  int ecol = col0 + wave * 16 + l15;
  float bs = bias[ecol];
#pragma unroll
  for (int mt = 0; mt < 4; ++mt)
#pragma unroll
    for (int rr = 0; rr < 4; ++rr) {
      int mrow = row0 + mt*16 + q*4 + rr;
      int b = mrow >> 9, t = mrow & 511;
      C[((size_t)t * 32 + b) * 1024 + ecol] = f2bf(acc[mt][rr] + bs);
    }
}

__global__ void __launch_bounds__(256) gemm_out_kernel(const short* __restrict__ A,
                                                       const short* __restrict__ Bp,
                                                       const float* __restrict__ bias,
                                                       const float* __restrict__ X,
                                                       float* __restrict__ Y) {
  __shared__ short At[64][72];
  int tid = threadIdx.x, wave = tid >> 6, lane = tid & 63, l15 = lane & 15, q = lane >> 4;
  int row0 = blockIdx.x * 64, col0 = blockIdx.y * 64;
  ffrag acc[4] = {{0,0,0,0},{0,0,0,0},{0,0,0,0},{0,0,0,0}};
  int nt = (col0 >> 4) + wave;
  const short* bp = Bp + (size_t)nt * 32 * 512 + lane * 8;
  int r = tid >> 2, cs = (tid & 3) * 16;
  const short* asrc = A + (size_t)(row0 + r) * 1024 + cs;
  for (int k0 = 0; k0 < 1024; k0 += 64) {
    __syncthreads();
    *(bfrag*)&At[r][cs]     = *(const bfrag*)(asrc + k0);
    *(bfrag*)&At[r][cs + 8] = *(const bfrag*)(asrc + k0 + 8);
    __syncthreads();
#pragma unroll
    for (int kk = 0; kk < 64; kk += 32) {
      bfrag b = *(const bfrag*)(bp + (size_t)((k0 + kk) >> 5) * 512);
#pragma unroll
      for (int mt = 0; mt < 4; ++mt) {
        bfrag a = *(const bfrag*)&At[mt*16 + l15][kk + q*8];
        acc[mt] = mfma16(a, b, acc[mt]);
      }
    }
  }
  int ecol = col0 + wave * 16 + l15;
  float bs = bias[ecol];
#pragma unroll
  for (int mt = 0; mt < 4; ++mt)
#pragma unroll
    for (int rr = 0; rr < 4; ++rr) {
      int mrow = row0 + mt*16 + q*4 + rr;
      int t = mrow >> 5, b = mrow & 31;
      size_t yi = ((size_t)b * 512 + t) * 1024 + ecol;
      Y[yi] = X[yi] + acc[mt][rr] + bs;
    }
}

// ----------------------------- scan -----------------------------------------
// 256 WGs: g0 = WG 0..63  (P1: A1 cols [sub*32, +32), K=2048 over [cfc_x|h])
//          g1 = WG 64..127(P2: A2 cols [sub*32, +32), K=2048 over A1)
//          g2 = WG 128..255(P3: u-cols [sub*8, +8) x {ff1,ff2,ta,tb}, K=2048 over A2)
// Weight slice (128 KB, frag order) staged in LDS once; survives buffer_inv.
__global__ void __launch_bounds__(256, 1) scan_kernel(
    const short* cfcx, const short* __restrict__ W0p, const short* __restrict__ W1p,
    const short* __restrict__ Wbp, const float* __restrict__ bbb,
    const float* __restrict__ bf1, const float* __restrict__ bf2,
    const float* __restrict__ bta, const float* __restrict__ btb,
    const float* __restrict__ tsp, short* __restrict__ A1, short* __restrict__ A2,
    short* __restrict__ hbuf, short* outs, float* __restrict__ hfinal,
    unsigned* flags) {
  __shared__ short wlds[2 * 64 * 64 * 8];   // 128 KB  [ntL][kt][lane][8]
  __shared__ float red[4][32][32];          // 16 KB   per-wave partials
  __shared__ float blds[32];                // bias slice

  const int w = blockIdx.x, tid = threadIdx.x;
  const int wave = tid >> 6, lane = tid & 63, l15 = lane & 15, q = lane >> 4;
  const int g   = (w < 64) ? 0 : (w < 128 ? 1 : 2);
  const int sub = w - (g == 0 ? 0 : (g == 1 ? 64 : 128));

  // ---- stage weight slice + bias into LDS (once) ----
  {
    const short* wsrc = (g == 0) ? (W0p + (size_t)sub * 65536)
                      : (g == 1) ? (W1p + (size_t)sub * 65536)
                      :            (Wbp + (size_t)sub * 65536);
    for (int i = tid; i < 8192; i += 256)
      ((bfrag*)wlds)[i] = ((const bfrag*)wsrc)[i];
    if (tid < 32) {
      float bv;
      if (g == 0)      bv = bbb[sub * 32 + tid];
      else if (g == 1) bv = bbb[2048 + sub * 32 + tid];
      else {
        int m = tid >> 3, col = sub * 8 + (tid & 7);
        bv = (m == 0 ? bf1 : m == 1 ? bf2 : m == 2 ? bta : btb)[col];
      }
      blds[tid] = bv;
    }
  }
  __syncthreads();

  const int erow = tid >> 3;                 // epilogue row (both layouts)
  const int euc  = tid & 7;

  for (int t = 0; t < 512; ++t) {
    const unsigned v = (unsigned)(t + 1);
    // ---- poll producers (P1 waits P3 of step t-1; P2 waits P1; P3 waits P2) ----
    {
      int lo, cnt; unsigned need;
      if (g == 0)      { lo = 128; cnt = 128; need = v - 1; }
      else if (g == 1) { lo = 0;   cnt = 64;  need = v; }
      else             { lo = 64;  cnt = 64;  need = v; }
      int ok;
      do {
        ok = 1;
        if (tid < cnt)
          ok = (__hip_atomic_load(&flags[lo + tid], __ATOMIC_RELAXED,
                                  __HIP_MEMORY_SCOPE_AGENT) >= need);
      } while (__syncthreads_and(ok) == 0);
      if (tid == 0) __threadfence();         // acquire: inv L1+L2 (weights in LDS, safe)
      __syncthreads();
    }

    float ts = (g == 2) ? tsp[erow * 512 + t] : 0.f;

    // ---- matmul: [32 x 2048] @ LDS slice -> per-wave K-partials in red ----
    {
      const short* Abase; int astr;
      if (g == 0) {
        Abase = ((wave < 2) ? (cfcx + ((size_t)t << 15)) : hbuf) + (wave & 1) * 512;
        astr = 1024;
      } else {
        Abase = (g == 1 ? A1 : A2) + wave * 512;
        astr = 2048;
      }
      const short* a0p = Abase + (size_t)l15 * astr + q * 8;
      const short* a1p = a0p + (size_t)16 * astr;
      const short* b0p = wlds + ((size_t)(wave * 16) * 64 + lane) * 8;
      const short* b1p = b0p + (size_t)64 * 64 * 8;
      ffrag c00 = {0,0,0,0}, c01 = {0,0,0,0}, c10 = {0,0,0,0}, c11 = {0,0,0,0};
#pragma unroll
      for (int ki = 0; ki < 16; ++ki) {
        bfrag a0 = *(const bfrag*)(a0p + ki * 32);
        bfrag a1 = *(const bfrag*)(a1p + ki * 32);
        bfrag b0 = *(const bfrag*)(b0p + ki * 512);
        bfrag b1 = *(const bfrag*)(b1p + ki * 512);
        c00 = mfma16(a0, b0, c00); c01 = mfma16(a0, b1, c01);
        c10 = mfma16(a1, b0, c10); c11 = mfma16(a1, b1, c11);
      }
#pragma unroll
      for (int rr = 0; rr < 4; ++rr) {
        red[wave][q*4 + rr][l15]           = c00[rr];
        red[wave][q*4 + rr][16 + l15]      = c01[rr];
        red[wave][16 + q*4 + rr][l15]      = c10[rr];
        red[wave][16 + q*4 + rr][16 + l15] = c11[rr];
      }
      __syncthreads();
    }

    // ---- epilogue ----
    if (g < 2) {
      short* dst = (g == 0 ? A1 : A2) + sub * 32;
      int cg = euc * 4;
      short tmp[4];
#pragma unroll
      for (int c = 0; c < 4; ++c) {
        int col = cg + c;
        float s = red[0][erow][col] + red[1][erow][col]
                + red[2][erow][col] + red[3][erow][col] + blds[col];
        tmp[c] = f2bf(1.7159f * tanhf(0.666f * s));
      }
      *(uint2*)(dst + (size_t)erow * 2048 + cg) =
          make_uint2(pack2(tmp[0], tmp[1]), pack2(tmp[2], tmp[3]));
    } else {
      int u = sub * 8 + euc;
      float s1 = red[0][erow][euc]      + red[1][erow][euc]      + red[2][erow][euc]      + red[3][erow][euc]      + blds[euc];
      float s2 = red[0][erow][8 + euc]  + red[1][erow][8 + euc]  + red[2][erow][8 + euc]  + red[3][erow][8 + euc]  + blds[8 + euc];
      float sa = red[0][erow][16 + euc] + red[1][erow][16 + euc] + red[2][erow][16 + euc] + red[3][erow][16 + euc] + blds[16 + euc];
      float sb = red[0][erow][24 + euc] + red[1][erow][24 + euc] + red[2][erow][24 + euc] + red[3][erow][24 + euc] + blds[24 + euc];
      float sg = 1.f / (1.f + expf(-(sa * ts + sb)));
      float hn = tanhf(s1) * (1.f - sg) + sg * tanhf(s2);
      short hb = f2bf(hn);
      hbuf[erow * 1024 + u] = hb;
      outs[((size_t)t * 32 + erow) * 1024 + u] = hb;   // overwrites dead cfc_x[t]
      if (t == 511) hfinal[erow * 1024 + u] = hn;
    }
    __syncthreads();                         // all waves drained (vmcnt0 at barrier)
    if (tid == 0) {
      __threadfence();                       // release: wbl2 pushes WG's stores to L3
      __hip_atomic_store(&flags[w], v, __ATOMIC_RELAXED, __HIP_MEMORY_SCOPE_AGENT);
    }
  }
}

// ----------------------------- launch ---------------------------------------
extern "C" void kernel_launch(void* const* d_in, const int* in_sizes, int n_in,
                              void* d_out, int out_size, void* d_ws, size_t ws_size,
                              hipStream_t stream) {
  (void)in_sizes; (void)n_in; (void)out_size; (void)ws_size;
  const float* x      = (const float*)d_in[0];
  const float* tsp    = (const float*)d_in[1];
  const float* hidden = (const float*)d_in[2];
  const float* norm_w = (const float*)d_in[3];
  const float* norm_b = (const float*)d_in[4];
  const float* w_in   = (const float*)d_in[5];
  const float* b_in   = (const float*)d_in[6];
  const float* bb_w   = (const float*)d_in[7];
  const float* bb_b   = (const float*)d_in[8];
  const float* w_ff1  = (const float*)d_in[9];
  const float* b_ff1  = (const float*)d_in[10];
  const float* w_ff2  = (const float*)d_in[11];
  const float* b_ff2  = (const float*)d_in[12];
  const float* w_ta   = (const float*)d_in[13];
  const float* b_ta   = (const float*)d_in[14];
  const float* w_tb   = (const float*)d_in[15];
  const float* b_tb   = (const float*)d_in[16];
  const float* w_out  = (const float*)d_in[17];
  const float* b_out  = (const float*)d_in[18];

  float* y      = (float*)d_out;
  float* hfinal = y + (size_t)32 * 512 * 1024;

  char* ws = (char*)d_ws;
  unsigned* flags = (unsigned*)(ws + OFF_FLAGS);
  short* cfcx  = (short*)(ws + OFF_CFCX);
  short* xn    = (short*)(ws + OFF_XN);
  short* A1    = (short*)(ws + OFF_A1);
  short* A2    = (short*)(ws + OFF_A2);
  short* hbuf  = (short*)(ws + OFF_H);
  short* winp  = (short*)(ws + OFF_WINP);
  short* w0p   = (short*)(ws + OFF_W0P);
  short* w1p   = (short*)(ws + OFF_W1P);
  short* wbp   = (short*)(ws + OFF_WBP);
  short* woutp = (short*)(ws + OFF_WOUTP);
  short* outs  = cfcx;   // outs[t] overwrites dead cfc_x[t] slice

  init_kernel<<<128, 256, 0, stream>>>(hidden, hbuf, flags);
  ln_kernel<<<16384, 256, 0, stream>>>(x, norm_w, norm_b, xn);

  pack_frag<<<2048, 64, 0, stream>>>(w_in, winp, 32, 1024);
  pack_frag<<<8192, 64, 0, stream>>>(bb_w, w0p, 64, 2048);
  pack_frag<<<8192, 64, 0, stream>>>(bb_w + (size_t)2048*2048, w1p, 64, 2048);
  pack_bb3<<<16384, 64, 0, stream>>>(w_ff1, w_ff2, w_ta, w_tb, wbp);
  pack_frag<<<2048, 64, 0, stream>>>(w_out, woutp, 32, 1024);

  gemm_in_kernel<<<dim3(256, 16), 256, 0, stream>>>(xn, winp, b_in, cfcx);

  void* args[] = {&cfcx, &w0p, &w1p, &wbp, &bb_b, &b_ff1, &b_ff2, &b_ta, &b_tb,
                  &tsp, &A1, &A2, &hbuf, &outs, &hfinal, &flags};
  hipLaunchCooperativeKernel(reinterpret_cast<const void*>(&scan_kernel),
                             dim3(256), dim3(256), args, 0, stream);

  gemm_out_kernel<<<dim3(256, 16), 256, 0, stream>>>(outs, woutp, b_out, x, y);
}